// Round 3
// baseline (103.174 us; speedup 1.0000x reference)
//
#include <hip/hip_runtime.h>
#include <hip/hip_bf16.h>

#define T_TOKENS 2048
#define DIM 256
#define NLEV 8

using bf16x8 = __attribute__((ext_vector_type(8))) short;
using f32x4  = __attribute__((ext_vector_type(4))) float;

__device__ __forceinline__ unsigned short f2bf(float f) {
    union { float f; unsigned u; } v; v.f = f;
    unsigned r = v.u + 0x7FFFu + ((v.u >> 16) & 1u);   // RNE
    return (unsigned short)(r >> 16);
}

// ---------------- Kernel 1: routing (exact fp32) ----------------
// wave per token: 8 levels of dot(x, w1[node]) with shuffle reduction.
__global__ __launch_bounds__(256) void route_kernel(
    const float* __restrict__ x, const float* __restrict__ w1s,
    const float* __restrict__ b1s,
    float* __restrict__ pw,   // [T][8]
    int*   __restrict__ pc)   // [T] pathcode in [256,511]
{
    int wave = threadIdx.x >> 6;
    int lane = threadIdx.x & 63;
    int t = blockIdx.x * 4 + wave;    // grid = 512 -> t < 2048

    const float4 xv = *reinterpret_cast<const float4*>(x + (size_t)t * DIM + lane * 4);
    int p = 1;
    float keep = 0.0f;
    #pragma unroll
    for (int lvl = 0; lvl < NLEV; ++lvl) {
        int node = p - 1;
        const float4 wv = *reinterpret_cast<const float4*>(w1s + (size_t)node * DIM + lane * 4);
        float s = xv.x * wv.x + xv.y * wv.y + xv.z * wv.z + xv.w * wv.w;
        #pragma unroll
        for (int off = 32; off; off >>= 1) s += __shfl_xor(s, off);
        float score = s + b1s[node];
        float a = fabsf(score);
        float g = a * 0.5f * (1.0f + erff(a * 0.70710678118654752f));  // exact GELU
        if (lane == lvl) keep = g;
        int choice = (score > 0.0f) ? 1 : 0;   // sign(0)->choice 0 matches ref
        p = 2 * p + choice;
    }
    if (lane < NLEV) pw[(size_t)t * NLEV + lane] = keep;
    if (lane == 0) pc[t] = p;
}

// ---------------- Kernel 2: counting sort by pathcode (1 block) ----------------
__global__ __launch_bounds__(256) void sort_kernel(
    const int* __restrict__ pc,
    int* __restrict__ order, int* __restrict__ spc)
{
    __shared__ int hist[256];
    __shared__ int offs[256];
    int tid = threadIdx.x;
    hist[tid] = 0;
    __syncthreads();

    int myPc[8];
    #pragma unroll
    for (int i = 0; i < 8; ++i) {
        int t = tid * 8 + i;
        myPc[i] = pc[t];
        atomicAdd(&hist[myPc[i] - 256], 1);
    }
    __syncthreads();

    if (tid < 64) {   // wave-0 exclusive scan over 256 bins (4 per lane)
        int lane = tid;
        int v0 = hist[lane * 4 + 0], v1 = hist[lane * 4 + 1];
        int v2 = hist[lane * 4 + 2], v3 = hist[lane * 4 + 3];
        int sum = v0 + v1 + v2 + v3;
        int scan = sum;
        #pragma unroll
        for (int off = 1; off < 64; off <<= 1) {
            int n = __shfl_up(scan, off);
            if (lane >= off) scan += n;
        }
        int excl = scan - sum;
        offs[lane * 4 + 0] = excl;
        offs[lane * 4 + 1] = excl + v0;
        offs[lane * 4 + 2] = excl + v0 + v1;
        offs[lane * 4 + 3] = excl + v0 + v1 + v2;
    }
    __syncthreads();

    #pragma unroll
    for (int i = 0; i < 8; ++i) {
        int t = tid * 8 + i;
        int bin = myPc[i] - 256;
        int pos = atomicAdd(&offs[bin], 1);
        order[pos] = t;
        spc[pos] = myPc[i];
    }
}

// ---------------- Kernel 3: path-weighted output via bf16 MFMA ----------------
// Wave-item = (16 sorted tokens) x (16 cols). grid = 128 tiles x 4 blocks,
// 256 threads (4 waves: colblocks). 2048 waves total -> 8 waves/CU.
// A fragments (16 tok x 256 k, bf16) live in 32 VGPRs, reused across all
// levels/segments. No LDS. bf16 conversion: proven manual-RNE f2bf.
__global__ __launch_bounds__(256) void out_kernel(
    const float* __restrict__ x, const float* __restrict__ w2s,
    const float* __restrict__ b2s, const float* __restrict__ pw,
    const int* __restrict__ order, const int* __restrict__ spc,
    float* __restrict__ out)
{
    int wv   = threadIdx.x >> 6;
    int lane = threadIdx.x & 63;
    int tileId  = blockIdx.x >> 2;                    // 0..127
    int colBase = ((blockIdx.x & 3) * 4 + wv) * 16;   // 0..240 step 16
    int row = lane & 15;
    int kg  = lane >> 4;                              // 0..3
    int base = tileId * 16;

    int tok  = order[base + row];
    int myPc = spc[base + row];

    // A fragments: afrag[ks] holds x[tok][ks*32 + kg*8 .. +7] as bf16
    bf16x8 afrag[8];
    #pragma unroll
    for (int ks = 0; ks < 8; ++ks) {
        const float* xp = x + (size_t)tok * DIM + ks * 32 + kg * 8;
        float4 a0 = *reinterpret_cast<const float4*>(xp);
        float4 a1 = *reinterpret_cast<const float4*>(xp + 4);
        bf16x8 av;
        av[0] = (short)f2bf(a0.x); av[1] = (short)f2bf(a0.y);
        av[2] = (short)f2bf(a0.z); av[3] = (short)f2bf(a0.w);
        av[4] = (short)f2bf(a1.x); av[5] = (short)f2bf(a1.y);
        av[6] = (short)f2bf(a1.z); av[7] = (short)f2bf(a1.w);
        afrag[ks] = av;
    }

    // path weights for my row (8 levels)
    float pwv[8];
    {
        float4 p0 = *reinterpret_cast<const float4*>(pw + (size_t)tok * NLEV);
        float4 p1 = *reinterpret_cast<const float4*>(pw + (size_t)tok * NLEV + 4);
        pwv[0] = p0.x; pwv[1] = p0.y; pwv[2] = p0.z; pwv[3] = p0.w;
        pwv[4] = p1.x; pwv[5] = p1.y; pwv[6] = p1.z; pwv[7] = p1.w;
    }

    f32x4 Oacc = {0.f, 0.f, 0.f, 0.f};

    #pragma unroll
    for (int lvl = 0; lvl < NLEV; ++lvl) {
        int key = myPc >> (NLEV - lvl);
        int prevKey = __shfl(key, (lane + 63) & 63);
        bool bnd = (row == 0) || (prevKey != key);
        unsigned long long bm = __ballot(bnd) & 0xFFFFull;  // groups replicate

        int s = 0;
        while (s < 16) {
            unsigned long long rest = bm >> (s + 1);
            int e = rest ? (s + (int)__ffsll((long long)rest)) : 16;
            int node = __shfl(key, s) - 1;

            const float* w2n = w2s + (size_t)node * DIM * DIM + colBase + (lane & 15);
            f32x4 acc = {0.f, 0.f, 0.f, 0.f};
            #pragma unroll
            for (int ks = 0; ks < 8; ++ks) {
                const float* wp = w2n + (size_t)(ks * 32 + kg * 8) * DIM;
                bf16x8 bv;
                bv[0] = (short)f2bf(wp[0 * DIM]);
                bv[1] = (short)f2bf(wp[1 * DIM]);
                bv[2] = (short)f2bf(wp[2 * DIM]);
                bv[3] = (short)f2bf(wp[3 * DIM]);
                bv[4] = (short)f2bf(wp[4 * DIM]);
                bv[5] = (short)f2bf(wp[5 * DIM]);
                bv[6] = (short)f2bf(wp[6 * DIM]);
                bv[7] = (short)f2bf(wp[7 * DIM]);
                acc = __builtin_amdgcn_mfma_f32_16x16x32_bf16(afrag[ks], bv, acc, 0, 0, 0);
            }

            float bias = b2s[(size_t)node * DIM + colBase + (lane & 15)];
            #pragma unroll
            for (int j = 0; j < 4; ++j) {
                int r = kg * 4 + j;
                float w = __shfl(pwv[lvl], r);
                float val = (r >= s && r < e) ? w : 0.0f;
                Oacc[j] += val * (acc[j] + bias);
            }
            s = e;
        }
    }

    #pragma unroll
    for (int j = 0; j < 4; ++j) {
        int r = kg * 4 + j;
        int otok = __shfl(tok, r);
        out[(size_t)otok * DIM + colBase + (lane & 15)] = Oacc[j];
    }
}

extern "C" void kernel_launch(void* const* d_in, const int* in_sizes, int n_in,
                              void* d_out, int out_size, void* d_ws, size_t ws_size,
                              hipStream_t stream) {
    const float* x   = (const float*)d_in[0];
    const float* w1s = (const float*)d_in[1];
    const float* b1s = (const float*)d_in[2];
    const float* w2s = (const float*)d_in[3];
    const float* b2s = (const float*)d_in[4];
    float* out = (float*)d_out;

    float* pw  = (float*)d_ws;                 // 2048*8 f32
    int* pc    = (int*)(pw + T_TOKENS * NLEV); // 2048
    int* order = pc + T_TOKENS;                // 2048
    int* spc   = order + T_TOKENS;             // 2048

    route_kernel<<<T_TOKENS / 4, 256, 0, stream>>>(x, w1s, b1s, pw, pc);
    sort_kernel<<<1, 256, 0, stream>>>(pc, order, spc);
    out_kernel<<<128 * 4, 256, 0, stream>>>(x, w2s, b2s, pw, order, spc, out);
}